// Round 8
// baseline (525.179 us; speedup 1.0000x reference)
//
#include <hip/hip_runtime.h>
#include <hip/hip_bf16.h>

#define NN 50000
#define NE 800000
#define NG 512

typedef __bf16 bf16_t;
typedef __bf16 bf16x8 __attribute__((ext_vector_type(8)));
typedef float f32x4 __attribute__((ext_vector_type(4)));
typedef float f32x2 __attribute__((ext_vector_type(2)));

__device__ __forceinline__ float lrelu(float v) { return v >= 0.f ? v : 0.01f * v; }

// unpack 2 bf16 (one u32) -> float2
__device__ __forceinline__ f32x2 unpk2(unsigned w) {
    union { unsigned u; float f; } lo, hi;
    lo.u = w << 16;
    hi.u = w & 0xffff0000u;
    f32x2 r; r[0] = lo.f; r[1] = hi.f; return r;
}
// pack 2 f32 -> 2 bf16 in one u32
__device__ __forceinline__ unsigned pk2(float a, float b) {
    union { bf16_t h[2]; unsigned u; } x;
    x.h[0] = (bf16_t)a; x.h[1] = (bf16_t)b; return x.u;
}

// ---------------- tiny precomputes ----------------
__global__ void gme_setup(const float* __restrict__ emb,
                          const float* __restrict__ c1lw, const float* __restrict__ c1l2w,
                          const float* __restrict__ c1l2b, const float* __restrict__ c1lb,
                          const float* __restrict__ c2lw, const float* __restrict__ c2l2w,
                          const float* __restrict__ c2l2b, const float* __restrict__ c2lb,
                          float* __restrict__ TY, float* __restrict__ WC1, float* __restrict__ CB1,
                          float* __restrict__ WC2, float* __restrict__ CB2,
                          bf16_t* __restrict__ W2B) {
    int b = blockIdx.x, t = threadIdx.x;
    if (b < 51) {
        const float* er = emb + b * 128;
        const float* wr = c1lw + t * 128;
        float s = 0.f;
        for (int k = 0; k < 128; ++k) s += er[k] * wr[k];
        TY[b * 256 + t] = s;
    } else if (b == 51) {
        const float* wr = c1lw + t * 128;
        float a0 = 0, a1 = 0, a2 = 0, a3 = 0, ab = 0;
        for (int k = 0; k < 128; ++k) {
            float w = wr[k];
            a0 += w * c1l2w[k * 4 + 0]; a1 += w * c1l2w[k * 4 + 1];
            a2 += w * c1l2w[k * 4 + 2]; a3 += w * c1l2w[k * 4 + 3];
            ab += w * c1l2b[k];
        }
        WC1[t * 4 + 0] = a0; WC1[t * 4 + 1] = a1; WC1[t * 4 + 2] = a2; WC1[t * 4 + 3] = a3;
        CB1[t] = ab + c1lb[t];
    } else if (b == 52) {
        const float* wr = c2lw + t * 256;
        float a0 = 0, a1 = 0, a2 = 0, a3 = 0, ab = 0;
        for (int k = 0; k < 256; ++k) {
            float w = wr[k];
            a0 += w * c2l2w[k * 4 + 0]; a1 += w * c2l2w[k * 4 + 1];
            a2 += w * c2l2w[k * 4 + 2]; a3 += w * c2l2w[k * 4 + 3];
            ab += w * c2l2b[k];
        }
        WC2[t * 4 + 0] = a0; WC2[t * 4 + 1] = a1; WC2[t * 4 + 2] = a2; WC2[t * 4 + 3] = a3;
        CB2[t] = ab + c2lb[t];
    } else {
        int i0 = (b - 53) * 1024;
        for (int r = 0; r < 4; ++r) {
            int i = i0 + r * 256 + t;
            W2B[i] = (bf16_t)c2lw[i];
        }
    }
}

// ---------------- CSR build ----------------
__global__ void gme_count(const int* __restrict__ ei, int* __restrict__ cnt) {
    int e = blockIdx.x * 256 + threadIdx.x;
    if (e >= NE) return;
    atomicAdd(&cnt[ei[NE + e]], 1);
}

__global__ void gme_scan1(const int* __restrict__ CNT, int* __restrict__ LP,
                          int* __restrict__ BS) {
    __shared__ int lds[256];
    int b = blockIdx.x, t = threadIdx.x;
    int i = b * 196 + t;
    int v = (t < 196 && i < NN) ? CNT[i] : 0;
    lds[t] = v;
    __syncthreads();
    for (int off = 1; off < 256; off <<= 1) {
        int u = (t >= off) ? lds[t - off] : 0;
        __syncthreads();
        lds[t] += u;
        __syncthreads();
    }
    if (t < 196 && i < NN) LP[i] = lds[t] - v;
    if (t == 255) BS[b] = lds[255];
}

__global__ void gme_scan2(const int* __restrict__ BS, int* __restrict__ BX,
                          int* __restrict__ RS) {
    __shared__ int lds[256];
    int t = threadIdx.x;
    int v = BS[t];
    lds[t] = v;
    __syncthreads();
    for (int off = 1; off < 256; off <<= 1) {
        int u = (t >= off) ? lds[t - off] : 0;
        __syncthreads();
        lds[t] += u;
        __syncthreads();
    }
    BX[t] = lds[t] - v;
    if (t == 255) RS[NN] = lds[255];
}

__global__ void gme_scan3(const int* __restrict__ LP, const int* __restrict__ BX,
                          int* __restrict__ RS, int* __restrict__ CUR) {
    int b = blockIdx.x, t = threadIdx.x;
    if (t >= 196) return;
    int i = b * 196 + t;
    if (i >= NN) return;
    int v = BX[b] + LP[i];
    RS[i] = v;
    CUR[i] = v;
}

// one 16B record per edge: {src, node_ids[src], attr01(bf16x2), attr23(bf16x2)}
__global__ void gme_scatter(const int* __restrict__ ei, const float4* __restrict__ eattr,
                            const int* __restrict__ node_ids,
                            int* __restrict__ CUR, uint4* __restrict__ REC) {
    int e = blockIdx.x * 256 + threadIdx.x;
    if (e >= NE) return;
    int s = ei[e];
    int d = ei[NE + e];
    float4 a = eattr[e];
    uint4 rec;
    rec.x = (unsigned)s;
    rec.y = (unsigned)node_ids[s];
    rec.z = pk2(a.x, a.y);
    rec.w = pk2(a.z, a.w);
    int pos = atomicAdd(&CUR[d], 1);
    REC[pos] = rec;
}

// ---------------- edge aggregation ----------------
// one wave per node, lane = 4 channels; 4-edge unroll; bf16 output
template <int BF>
__global__ __launch_bounds__(256, 8) void gme_conv(
        const int* __restrict__ RS, const uint4* __restrict__ REC,
        const float* __restrict__ TY, const bf16_t* __restrict__ QB,
        const float* __restrict__ Wc, const float* __restrict__ cb,
        bf16_t* __restrict__ PB) {
    int lane = threadIdx.x & 63;
    int node = blockIdx.x * 4 + (threadIdx.x >> 6);
    if (node >= NN) return;
    const float4* wc4 = (const float4*)Wc;
    int c4 = lane * 4;
    float4 w0 = wc4[c4 + 0], w1 = wc4[c4 + 1], w2 = wc4[c4 + 2], w3 = wc4[c4 + 3];
    float4 bz4 = ((const float4*)cb)[lane];
    f32x2 wA0 = {w0.x, w1.x}, wB0 = {w0.y, w1.y}, wC0 = {w0.z, w1.z}, wD0 = {w0.w, w1.w};
    f32x2 wA1 = {w2.x, w3.x}, wB1 = {w2.y, w3.y}, wC1 = {w2.z, w3.z}, wD1 = {w2.w, w3.w};
    f32x2 bz0 = {bz4.x, bz4.y}, bz1 = {bz4.z, bz4.w};
    const f32x2 zero = {0.f, 0.f};
    const f32x2 slope = {0.01f, 0.01f};
    f32x2 acc0 = zero, acc1 = zero;
    int rs = RS[node], re = RS[node + 1];

    struct Row { f32x2 y0, y1; };
    auto rowld = [&](unsigned row) -> Row {
        Row r;
        if (BF) {
            uint2 u = *((const uint2*)(QB + row * 256) + lane);
            r.y0 = unpk2(u.x);
            r.y1 = unpk2(u.y);
        } else {
            float4 y = *((const float4*)(TY + row * 256) + lane);
            r.y0[0] = y.x; r.y0[1] = y.y;
            r.y1[0] = y.z; r.y1[1] = y.w;
        }
        return r;
    };
    auto accum = [&](uint4 rec, Row r) {
        f32x2 a01 = unpk2(rec.z), a23 = unpk2(rec.w);
        f32x2 ax = {a01[0], a01[0]}, ay = {a01[1], a01[1]};
        f32x2 az = {a23[0], a23[0]}, aw = {a23[1], a23[1]};
        f32x2 m0 = __builtin_elementwise_fma(ax, wA0, bz0);
        f32x2 m1 = __builtin_elementwise_fma(ax, wA1, bz1);
        m0 = __builtin_elementwise_fma(ay, wB0, m0);
        m1 = __builtin_elementwise_fma(ay, wB1, m1);
        m0 = __builtin_elementwise_fma(az, wC0, m0);
        m1 = __builtin_elementwise_fma(az, wC1, m1);
        m0 = __builtin_elementwise_fma(aw, wD0, m0);
        m1 = __builtin_elementwise_fma(aw, wD1, m1);
        m0 += r.y0;
        m1 += r.y1;
        acc0 += __builtin_elementwise_max(m0, zero);
        acc1 += __builtin_elementwise_max(m1, zero);
        acc0 = __builtin_elementwise_fma(__builtin_elementwise_min(m0, zero), slope, acc0);
        acc1 = __builtin_elementwise_fma(__builtin_elementwise_min(m1, zero), slope, acc1);
    };

    int j = rs;
    for (; j + 4 <= re; j += 4) {
        uint4 e0 = REC[j], e1 = REC[j + 1], e2 = REC[j + 2], e3 = REC[j + 3];
        Row r0 = rowld(BF ? e0.x : e0.y);
        Row r1 = rowld(BF ? e1.x : e1.y);
        Row r2 = rowld(BF ? e2.x : e2.y);
        Row r3 = rowld(BF ? e3.x : e3.y);
        accum(e0, r0); accum(e1, r1); accum(e2, r2); accum(e3, r3);
    }
    for (; j < re; ++j) {
        uint4 e0 = REC[j];
        accum(e0, rowld(BF ? e0.x : e0.y));
    }
    uint2 outp;
    outp.x = pk2(acc0[0], acc0[1]);
    outp.y = pk2(acc1[0], acc1[1]);
    *((uint2*)(PB + node * 256) + lane) = outp;
}

// ---------------- BN stats: two-stage, atomic-free, bf16 input ----------------
__global__ __launch_bounds__(256) void gme_bns1(const bf16_t* __restrict__ PB,
                                                float* __restrict__ PART) {
    __shared__ float ls[4][256], lq[4][256];
    int lane = threadIdx.x & 63;
    int w = threadIdx.x >> 6;
    int b = blockIdx.x;
    int r0 = b * 98;
    int r1 = r0 + 98; if (r1 > NN) r1 = NN;
    f32x2 s0 = {0, 0}, s1 = {0, 0}, q0 = {0, 0}, q1 = {0, 0};
    for (int n = r0 + w; n < r1; n += 4) {
        uint2 u = ((const uint2*)(PB + n * 256))[lane];
        f32x2 v0 = unpk2(u.x), v1 = unpk2(u.y);
        s0 += v0; s1 += v1;
        q0 = __builtin_elementwise_fma(v0, v0, q0);
        q1 = __builtin_elementwise_fma(v1, v1, q1);
    }
    int c = lane * 4;
    ls[w][c] = s0[0]; ls[w][c + 1] = s0[1]; ls[w][c + 2] = s1[0]; ls[w][c + 3] = s1[1];
    lq[w][c] = q0[0]; lq[w][c + 1] = q0[1]; lq[w][c + 2] = q1[0]; lq[w][c + 3] = q1[1];
    __syncthreads();
    if (w == 0) {
#pragma unroll
        for (int k = 0; k < 4; ++k) {
            int cc = c + k;
            PART[b * 512 + cc] = ls[0][cc] + ls[1][cc] + ls[2][cc] + ls[3][cc];
            PART[b * 512 + 256 + cc] = lq[0][cc] + lq[1][cc] + lq[2][cc] + lq[3][cc];
        }
    }
}

__global__ __launch_bounds__(512) void gme_bns2(const float* __restrict__ PART,
                                                float* __restrict__ ST) {
    int t = threadIdx.x;
    float acc = 0.f;
#pragma unroll 8
    for (int r = 0; r < 512; ++r) acc += PART[r * 512 + t];
    ST[t] = acc;
}

// ---------------- GEMM: lrelu(bn1(PB)) @ W2^T -> bf16 QB ----------------
__global__ __launch_bounds__(256) void gme_gemm(const bf16_t* __restrict__ PB,
                                                const float* __restrict__ ST,
                                                const float* __restrict__ bw,
                                                const float* __restrict__ bb,
                                                const bf16_t* __restrict__ W2B,
                                                bf16_t* __restrict__ QB) {
    __shared__ float s_sc[256], s_sh[256];
    {
        int c = threadIdx.x;
        float mean = ST[c] * (1.f / NN);
        float var = ST[256 + c] * (1.f / NN) - mean * mean;
        float sc = bw[c] * rsqrtf(var + 1e-5f);
        s_sc[c] = sc;
        s_sh[c] = bb[c] - mean * sc;
    }
    __syncthreads();
    int lane = threadIdx.x & 63;
    int wave = blockIdx.x * 4 + (threadIdx.x >> 6);
    if (wave >= NN / 16) return;
    int m0 = wave * 16;
    int r = lane & 15, q = lane >> 4;
    const uint4* arow = (const uint4*)(PB + (m0 + r) * 256);
    bf16x8 a[8];
#pragma unroll
    for (int kt = 0; kt < 8; ++kt) {
        int k0 = kt * 32 + q * 8;
        uint4 u = arow[kt * 4 + q];
        f32x2 p0 = unpk2(u.x), p1 = unpk2(u.y), p2 = unpk2(u.z), p3 = unpk2(u.w);
        union { bf16x8 v; unsigned u32[4]; } f;
        f.u32[0] = pk2(lrelu(fmaf(p0[0], s_sc[k0 + 0], s_sh[k0 + 0])),
                       lrelu(fmaf(p0[1], s_sc[k0 + 1], s_sh[k0 + 1])));
        f.u32[1] = pk2(lrelu(fmaf(p1[0], s_sc[k0 + 2], s_sh[k0 + 2])),
                       lrelu(fmaf(p1[1], s_sc[k0 + 3], s_sh[k0 + 3])));
        f.u32[2] = pk2(lrelu(fmaf(p2[0], s_sc[k0 + 4], s_sh[k0 + 4])),
                       lrelu(fmaf(p2[1], s_sc[k0 + 5], s_sh[k0 + 5])));
        f.u32[3] = pk2(lrelu(fmaf(p3[0], s_sc[k0 + 6], s_sh[k0 + 6])),
                       lrelu(fmaf(p3[1], s_sc[k0 + 7], s_sh[k0 + 7])));
        a[kt] = f.v;
    }
#pragma unroll
    for (int nt = 0; nt < 16; ++nt) {
        f32x4 acc = {0.f, 0.f, 0.f, 0.f};
        const bf16_t* brow = W2B + (nt * 16 + r) * 256 + q * 8;
#pragma unroll
        for (int kt = 0; kt < 8; ++kt) {
            bf16x8 bfrag = *(const bf16x8*)(brow + kt * 32);
            acc = __builtin_amdgcn_mfma_f32_16x16x32_bf16(a[kt], bfrag, acc, 0, 0, 0);
        }
        bf16_t* yo = QB + (m0 + q * 4) * 256 + nt * 16 + r;
        yo[0] = (bf16_t)acc[0]; yo[256] = (bf16_t)acc[1];
        yo[512] = (bf16_t)acc[2]; yo[768] = (bf16_t)acc[3];
    }
}

// ---------------- gate (BN2 on the fly, PB raw) ----------------
__global__ __launch_bounds__(256) void gme_x2g(const bf16_t* __restrict__ PB,
                                               const float* __restrict__ ST,
                                               const float* __restrict__ bw,
                                               const float* __restrict__ bb,
                                               const float* __restrict__ gw,
                                               const float* __restrict__ gb,
                                               float* __restrict__ GATE) {
    int lane = threadIdx.x & 63;
    int node = blockIdx.x * 4 + (threadIdx.x >> 6);
    if (node >= NN) return;
    float4 s = ((const float4*)ST)[lane];
    float4 qq = ((const float4*)(ST + 256))[lane];
    float4 w = ((const float4*)bw)[lane];
    float4 b = ((const float4*)bb)[lane];
    float4 g = ((const float4*)gw)[lane];
    float m0 = s.x * (1.f / NN), m1 = s.y * (1.f / NN), m2 = s.z * (1.f / NN), m3 = s.w * (1.f / NN);
    float sc0 = w.x * rsqrtf(qq.x * (1.f / NN) - m0 * m0 + 1e-5f);
    float sc1 = w.y * rsqrtf(qq.y * (1.f / NN) - m1 * m1 + 1e-5f);
    float sc2 = w.z * rsqrtf(qq.z * (1.f / NN) - m2 * m2 + 1e-5f);
    float sc3 = w.w * rsqrtf(qq.w * (1.f / NN) - m3 * m3 + 1e-5f);
    float sh0 = b.x - m0 * sc0, sh1 = b.y - m1 * sc1, sh2 = b.z - m2 * sc2, sh3 = b.w - m3 * sc3;
    uint2 u = ((const uint2*)(PB + node * 256))[lane];
    f32x2 p01 = unpk2(u.x), p23 = unpk2(u.y);
    float v0 = lrelu(fmaf(p01[0], sc0, sh0));
    float v1 = lrelu(fmaf(p01[1], sc1, sh1));
    float v2 = lrelu(fmaf(p23[0], sc2, sh2));
    float v3 = lrelu(fmaf(p23[1], sc3, sh3));
    float dot = v0 * g.x + v1 * g.y + v2 * g.z + v3 * g.w;
#pragma unroll
    for (int off = 32; off > 0; off >>= 1) dot += __shfl_xor(dot, off, 64);
    if (lane == 0) GATE[node] = dot + gb[0];
}

// ---------------- graph segment boundaries ----------------
__global__ void gme_gstart(const int* __restrict__ batch, int* __restrict__ GS) {
    int n = blockIdx.x * 256 + threadIdx.x;
    if (n >= NN) return;
    int b = batch[n];
    if (n == 0) {
        for (int g = 0; g <= b; ++g) GS[g] = 0;
    } else {
        int a = batch[n - 1];
        for (int g = a + 1; g <= b; ++g) GS[g] = n;
    }
    if (n == NN - 1) {
        for (int g = b + 1; g <= NG; ++g) GS[g] = NN;
    }
}

// ---------------- attention: LDS-staged weights, BN2+lrelu inline ----------------
__global__ void gme_attn(const int* __restrict__ GS, const float* __restrict__ GATE,
                         const bf16_t* __restrict__ PB, const float* __restrict__ ST,
                         const float* __restrict__ bw, const float* __restrict__ bb,
                         float* __restrict__ out) {
    __shared__ float red[256];
    __shared__ float wlds[1024];
    int g = blockIdx.x, t = threadIdx.x;
    int lo = GS[g], hi = GS[g + 1];
    if (lo >= hi) { out[g * 256 + t] = 0.f; return; }
    float mean = ST[t] * (1.f / NN);
    float var = ST[256 + t] * (1.f / NN) - mean * mean;
    float sc = bw[t] * rsqrtf(var + 1e-5f);
    float sh = bb[t] - mean * sc;
    float lm = -3.0e38f;
    for (int n = lo + t; n < hi; n += 256) lm = fmaxf(lm, GATE[n]);
    red[t] = lm; __syncthreads();
    for (int s = 128; s > 0; s >>= 1) { if (t < s) red[t] = fmaxf(red[t], red[t + s]); __syncthreads(); }
    float m = red[0]; __syncthreads();
    float ls = 0.f;
    for (int n = lo + t; n < hi; n += 256) ls += expf(GATE[n] - m);
    red[t] = ls; __syncthreads();
    for (int s = 128; s > 0; s >>= 1) { if (t < s) red[t] += red[t + s]; __syncthreads(); }
    float sinv = 1.f / red[0];
    float acc = 0.f;
    for (int base = lo; base < hi; base += 1024) {
        int csz = hi - base; if (csz > 1024) csz = 1024;
        __syncthreads();
        for (int i = t; i < csz; i += 256) wlds[i] = expf(GATE[base + i] - m);
        __syncthreads();
        int i = 0;
        for (; i + 2 <= csz; i += 2) {
            float p0 = (float)PB[(base + i) * 256 + t];
            float p1 = (float)PB[(base + i + 1) * 256 + t];
            acc = fmaf(wlds[i], lrelu(fmaf(p0, sc, sh)), acc);
            acc = fmaf(wlds[i + 1], lrelu(fmaf(p1, sc, sh)), acc);
        }
        if (i < csz) {
            float p0 = (float)PB[(base + i) * 256 + t];
            acc = fmaf(wlds[i], lrelu(fmaf(p0, sc, sh)), acc);
        }
    }
    out[g * 256 + t] = acc * sinv;
}

extern "C" void kernel_launch(void* const* d_in, const int* in_sizes, int n_in,
                              void* d_out, int out_size, void* d_ws, size_t ws_size,
                              hipStream_t stream) {
    const int* node_ids = (const int*)d_in[0];
    const int* edge_index = (const int*)d_in[1];
    const float4* edge_attr = (const float4*)d_in[2];
    const int* batch = (const int*)d_in[3];
    const float* emb = (const float*)d_in[4];
    const float* c1l2w = (const float*)d_in[5];
    const float* c1l2b = (const float*)d_in[6];
    const float* c1lw = (const float*)d_in[7];
    const float* c1lb = (const float*)d_in[8];
    const float* bn1w = (const float*)d_in[9];
    const float* bn1b = (const float*)d_in[10];
    const float* c2l2w = (const float*)d_in[11];
    const float* c2l2b = (const float*)d_in[12];
    const float* c2lw = (const float*)d_in[13];
    const float* c2lb = (const float*)d_in[14];
    const float* bn2w = (const float*)d_in[15];
    const float* bn2b = (const float*)d_in[16];
    const float* gate_w = (const float*)d_in[17];
    const float* gate_b = (const float*)d_in[18];

    char* ws = (char*)d_ws;
    size_t oPB = 0;                       // bf16 [50000,256]
    size_t oQB = oPB + 25600000;          // bf16 [50000,256]
    size_t oREC = oQB + 25600000;         // uint4 [800000]
    size_t oRS = oREC + 12800000;         // int [50001]
    size_t oCNT = oRS + 200064;           // int [50000]
    size_t oCUR = oCNT + 200000;          // int [50000]
    size_t oLP = oCUR + 200000;           // int [50000]
    size_t oBS = oLP + 200000;            // int [256]
    size_t oBX = oBS + 1024;              // int [256]
    size_t oTY = oBX + 1024;              // f32 [51,256]
    size_t oWC1 = oTY + 52224;            // f32 [256,4]
    size_t oCB1 = oWC1 + 4096;            // f32 [256]
    size_t oWC2 = oCB1 + 1024;            // f32 [256,4]
    size_t oCB2 = oWC2 + 4096;            // f32 [256]
    size_t oW2B = oCB2 + 1024;            // bf16 [256,256]
    size_t oST = oW2B + 131072;           // f32 [1024]: ST1+ST2
    size_t oGATE = oST + 4096;            // f32 [50000]
    size_t oGS = oGATE + 200000;          // int [513] (pad to 2064)
    size_t oPART = oGS + 2064;            // f32 [512*512]

    bf16_t* PB = (bf16_t*)(ws + oPB);
    bf16_t* QB = (bf16_t*)(ws + oQB);
    uint4* REC = (uint4*)(ws + oREC);
    int* RS = (int*)(ws + oRS);
    int* CNT = (int*)(ws + oCNT);
    int* CUR = (int*)(ws + oCUR);
    int* LP = (int*)(ws + oLP);
    int* BS = (int*)(ws + oBS);
    int* BX = (int*)(ws + oBX);
    float* TY = (float*)(ws + oTY);
    float* WC1 = (float*)(ws + oWC1);
    float* CB1 = (float*)(ws + oCB1);
    float* WC2 = (float*)(ws + oWC2);
    float* CB2 = (float*)(ws + oCB2);
    bf16_t* W2B = (bf16_t*)(ws + oW2B);
    float* ST1 = (float*)(ws + oST);
    float* ST2 = ST1 + 512;
    float* GATE = (float*)(ws + oGATE);
    int* GS = (int*)(ws + oGS);
    float* PART = (float*)(ws + oPART);

    hipMemsetAsync(CNT, 0, NN * sizeof(int), stream);

    gme_setup<<<117, 256, 0, stream>>>(emb, c1lw, c1l2w, c1l2b, c1lb,
                                       c2lw, c2l2w, c2l2b, c2lb,
                                       TY, WC1, CB1, WC2, CB2, W2B);
    gme_count<<<NE / 256, 256, 0, stream>>>(edge_index, CNT);
    gme_scan1<<<256, 256, 0, stream>>>(CNT, LP, BS);
    gme_scan2<<<1, 256, 0, stream>>>(BS, BX, RS);
    gme_scan3<<<256, 256, 0, stream>>>(LP, BX, RS, CUR);
    gme_scatter<<<NE / 256, 256, 0, stream>>>(edge_index, edge_attr, node_ids,
                                              CUR, REC);
    gme_gstart<<<(NN + 255) / 256, 256, 0, stream>>>(batch, GS);
    // conv1: rows from f32 TY via rec.y (node_ids[src])
    gme_conv<0><<<NN / 4, 256, 0, stream>>>(RS, REC, TY, nullptr, WC1, CB1, PB);
    gme_bns1<<<512, 256, 0, stream>>>(PB, PART);
    gme_bns2<<<1, 512, 0, stream>>>(PART, ST1);
    gme_gemm<<<(NN / 16 + 3) / 4, 256, 0, stream>>>(PB, ST1, bn1w, bn1b, W2B, QB);
    // conv2: rows from bf16 QB via rec.x (src)
    gme_conv<1><<<NN / 4, 256, 0, stream>>>(RS, REC, nullptr, QB, WC2, CB2, PB);
    gme_bns1<<<512, 256, 0, stream>>>(PB, PART);
    gme_bns2<<<1, 512, 0, stream>>>(PART, ST2);
    gme_x2g<<<NN / 4, 256, 0, stream>>>(PB, ST2, bn2w, bn2b, gate_w, gate_b, GATE);
    gme_attn<<<NG, 256, 0, stream>>>(GS, GATE, PB, ST2, bn2w, bn2b, (float*)d_out);
}